// Round 8
// baseline (1068.974 us; speedup 1.0000x reference)
//
#include <hip/hip_runtime.h>

// MultiHeadElman scan, R8: all-VALU cross-lane via BUILTINS ONLY (no inline
// asm -> no operand-aliasing hazard, which is what killed R4/R5).
// h_{t+1} = softsign(R@h + Wx@x_t + bias), T=4096, 256 chains (b,h),
// one 64-lane wave per chain. Lane layout: q = l&15, g = l>>4.
//   g0: rows 0-15 /j-lo   g1: rows 16-31 /j-hi
//   g2: rows 0-15 /j-hi   g3: rows 16-31 /j-lo
// Invariant: entering a step, lane holds hn of its OWN row; after the
// permlane16 fix every lane's hd = h[joff+q]; DPP ROW_ROR delivers
// h[joff+((q-+k)&15)] (direction probed, weights pre-permuted to match).
// Half-combine via permlane32_swap builtin: ret.x+ret.y == own+partner
// under either operand convention. x staged per 16-step block through LDS.

constexpr int T_STEPS = 4096;
constexpr int B_SZ    = 4;
constexpr int D_SZ    = 2048;
constexpr int H_SZ    = 64;
constexpr int HD      = 32;
constexpr long ST     = (long)B_SZ * D_SZ;   // 8192 floats per t
constexpr int BLK     = 16;                  // steps per x staging block

typedef unsigned int v2u __attribute__((ext_vector_type(2)));

#if __has_builtin(__builtin_amdgcn_permlane16_swap) && \
    __has_builtin(__builtin_amdgcn_permlane32_swap)
#define HAVE_PERMLANE 1
#else
#define HAVE_PERMLANE 0
#endif

// DPP ROW_ROR:N (ctrl 0x120+N) within each 16-lane row. Pure VALU.
template<int N>
__device__ __forceinline__ float ror16(float v) {
    if constexpr (N == 0) {
        return v;
    } else {
        return __int_as_float(__builtin_amdgcn_update_dpp(
            __float_as_int(v), __float_as_int(v),
            0x120 + N, 0xF, 0xF, false));
    }
}

__global__ __launch_bounds__(64, 1)
void elman_fused(const float* __restrict__ x,
                 const float* __restrict__ h0,
                 const float* __restrict__ R,
                 const float* __restrict__ Wx,
                 const float* __restrict__ bias,
                 float* __restrict__ out)
{
    const int l = threadIdx.x & 63;
    const int q = l & 15;
    const int g = l >> 4;
    const int joff = (g == 1 || g == 2) ? 16 : 0;   // j-half this lane covers
    const int row  = (g & 1) ? 16 + q : q;          // output row this lane owns
    const int h = blockIdx.x & (H_SZ - 1);
    const int b = blockIdx.x >> 6;
    const bool low32 = (l < 32);

    // ---- init-time convention probes (builtins only; SSA-clean) ----
    const int pr = __builtin_amdgcn_update_dpp(l, l, 0x121, 0xF, 0xF, false);
    const bool ror_minus = ((pr & 15) == ((q - 1) & 15));
#if HAVE_PERMLANE
    const v2u pp = __builtin_amdgcn_permlane16_swap((unsigned)l, (unsigned)l,
                                                    false, false);
    const bool sel_x = (pp.x == (unsigned)(l ^ 16)); // which output holds l^16
#endif

    // ---- weights pre-permuted to the probed rotation direction ----
    float rw[16], ww[16];
    {
        const float* Rrow = R  + (h * HD + row) * HD + joff;
        const float* Wrow = Wx + (h * HD + row) * HD + joff;
        if (ror_minus) {
#pragma unroll
            for (int k = 0; k < 16; ++k) {
                const int j = (q - k) & 15;
                rw[k] = Rrow[j];  ww[k] = Wrow[j];
            }
        } else {
#pragma unroll
            for (int k = 0; k < 16; ++k) {
                const int j = (q + k) & 15;
                rw[k] = Rrow[j];  ww[k] = Wrow[j];
            }
        }
    }
    // each j-half carries bias/2; the half-combine restores the full bias
    const float bias_half = 0.5f * bias[h * HD + row];

    float hn = h0[(b * H_SZ + h) * HD + row];       // own row's h

    // ---- x staging: 2 x 16 steps x 32 cols = 4 KB LDS ----
    __shared__ __align__(16) float xl[2][BLK][32];
    const int sk = l >> 2;                // step this lane stages
    const int sc = (l & 3) * 8;           // 8 columns per lane
    const float* xs = x + (long)sk * ST + (long)b * D_SZ + h * HD + sc;
    float*       op = out + (long)b * D_SZ + h * HD + row;

    // prologue: stage block 0 (one-time stall)
    {
        const float4* gsrc = (const float4*)xs;
        float4 v0 = gsrc[0], v1 = gsrc[1];
        float4* d = (float4*)(&xl[0][sk][sc]);
        d[0] = v0; d[1] = v1;
    }
    float xc = xl[0][0][joff + q];   // same-wave LDS RAW: pipe-ordered, safe

    for (int tb = 0; tb < T_STEPS; tb += BLK) {
        const int buf   = (tb >> 4) & 1;
        const bool more = (tb + BLK) < T_STEPS;

        // issue next block's global loads at block top (hidden under compute)
        float4 n0, n1;
        if (more) {
            const float4* gsrc = (const float4*)(xs + (long)(tb + BLK) * ST);
            n0 = gsrc[0]; n1 = gsrc[1];
        }

#pragma unroll
        for (int k = 0; k < BLK; ++k) {
            // prefetch next step's x (broadcast read, off chain)
            float xnext = 0.0f;
            if (k < BLK - 1) xnext = xl[buf][k + 1][joff + q];

            // dot-ready h: g0/g1 own hn; g2/g3 take lane l^16's (probed sel)
#if HAVE_PERMLANE
            const v2u hp = __builtin_amdgcn_permlane16_swap(
                __float_as_uint(hn), __float_as_uint(hn), false, false);
            const float from16 = __uint_as_float(sel_x ? hp.x : hp.y);
#else
            const float from16 = __int_as_float(__builtin_amdgcn_ds_swizzle(
                __float_as_int(hn), 0x401F));   // xor lane^16
#endif
            const float hd = low32 ? hn : from16;

            // 32 FMAs, 8 accumulators: W-chains off-chain, R-chains on-chain
            float w0 = fmaf(ww[0], xc, bias_half);
            float w1 = ww[1] * ror16<1>(xc);
            float w2 = ww[2] * ror16<2>(xc);
            float w3 = ww[3] * ror16<3>(xc);
            float r0 = rw[0] * hd;
            float r1 = rw[1] * ror16<1>(hd);
            float r2 = rw[2] * ror16<2>(hd);
            float r3 = rw[3] * ror16<3>(hd);
#define ACC4(B) \
            w0 = fmaf(ww[(B)+0], ror16<(B)+0>(xc), w0); \
            w1 = fmaf(ww[(B)+1], ror16<(B)+1>(xc), w1); \
            w2 = fmaf(ww[(B)+2], ror16<(B)+2>(xc), w2); \
            w3 = fmaf(ww[(B)+3], ror16<(B)+3>(xc), w3); \
            r0 = fmaf(rw[(B)+0], ror16<(B)+0>(hd), r0); \
            r1 = fmaf(rw[(B)+1], ror16<(B)+1>(hd), r1); \
            r2 = fmaf(rw[(B)+2], ror16<(B)+2>(hd), r2); \
            r3 = fmaf(rw[(B)+3], ror16<(B)+3>(hd), r3);
            ACC4(4)
            ACC4(8)
            ACC4(12)
#undef ACC4
            const float s = ((r0 + r1) + (r2 + r3))
                          + ((w0 + w1) + (w2 + w3));

            // half-combine: {ret.x, ret.y} == {own, partner} either way
#if HAVE_PERMLANE
            const v2u sp = __builtin_amdgcn_permlane32_swap(
                __float_as_uint(s), __float_as_uint(s), false, false);
            const float pre = __uint_as_float(sp.x) + __uint_as_float(sp.y);
#else
            const float pre = s + __shfl_xor(s, 32, 64);
#endif

            // softsign via v_rcp_f32 (~1 ulp; recurrence contractive)
            hn = pre * __builtin_amdgcn_rcpf(1.0f + fabsf(pre));

            // duplicate stores: partner lanes write identical value/addr
            op[0] = hn;
            op += ST;

            if (k < BLK - 1) xc = xnext;
        }

        // block bottom: commit next block's x, then pre-read its step 0
        if (more) {
            float4* d = (float4*)(&xl[buf ^ 1][sk][sc]);
            d[0] = n0; d[1] = n1;
            xc = xl[buf ^ 1][0][joff + q];  // same-wave RAW: ordered
        }
    }

    // h_final after ys (duplicates identical -> safe)
    out[(long)T_STEPS * ST + (b * H_SZ + h) * HD + row] = hn;
}

extern "C" void kernel_launch(void* const* d_in, const int* in_sizes, int n_in,
                              void* d_out, int out_size, void* d_ws, size_t ws_size,
                              hipStream_t stream) {
    const float* x    = (const float*)d_in[0];
    const float* h0   = (const float*)d_in[1];
    const float* R    = (const float*)d_in[2];
    const float* Wx   = (const float*)d_in[3];
    const float* bias = (const float*)d_in[4];
    float* out = (float*)d_out;

    elman_fused<<<dim3(B_SZ * H_SZ), dim3(64), 0, stream>>>(x, h0, R, Wx, bias, out);
}

// Round 10
// 628.230 us; speedup vs baseline: 1.7016x; 1.7016x over previous
//
#include <hip/hip_runtime.h>

// MultiHeadElman scan, R10 (= R9 with __fp16 vector types fixed).
//  - Scan (per step, proven R8 math): permlane16-fix -> 15x DPP row_ror ->
//    16 R-FMAs -> permlane32 half-combine -> softsign. ~50 VALU, no LDS on
//    the h-chain. Inner loop FORCED ROLLED (blocks scheduler load-sinking).
//  - W-x projection: per 16-step block, wx = x_blk * W^T + bias computed by
//    TWO mfma_f32_16x16x32_f16 (A = x f16, B = W^T f16 loaded once, bias in
//    C-init). Results in LDS wxl; scan reads 1 broadcast float/step.
//  - x staged via global_load_lds (cannot be sunk by the compiler), drained
//    with in-order vmcnt(16) so the 16 younger ys-stores stay in flight.
// Lane layout (q,g) as R8: g0 rows0-15/j-lo, g1 rows16-31/j-hi,
//                          g2 rows0-15/j-hi, g3 rows16-31/j-lo.

typedef __fp16 f16x2 __attribute__((ext_vector_type(2)));
typedef __fp16 f16x8 __attribute__((ext_vector_type(8)));
typedef float  f32x4 __attribute__((ext_vector_type(4)));
typedef unsigned int v2u __attribute__((ext_vector_type(2)));

constexpr int T_STEPS = 4096;
constexpr int B_SZ    = 4;
constexpr int D_SZ    = 2048;
constexpr int H_SZ    = 64;
constexpr int HD      = 32;
constexpr long ST     = (long)B_SZ * D_SZ;   // 8192 floats per t
constexpr int BLK     = 16;                  // steps per block

typedef const __attribute__((address_space(1))) void* gas_t;
typedef __attribute__((address_space(3))) void*       las_t;

// DPP ROW_ROR:N within each 16-lane row (pure VALU).
template<int N>
__device__ __forceinline__ float ror16(float v) {
    if constexpr (N == 0) {
        return v;
    } else {
        return __int_as_float(__builtin_amdgcn_update_dpp(
            __float_as_int(v), __float_as_int(v),
            0x120 + N, 0xF, 0xF, false));
    }
}

__global__ __launch_bounds__(64, 1)
void elman_fused(const float* __restrict__ x,
                 const float* __restrict__ h0,
                 const float* __restrict__ R,
                 const float* __restrict__ Wx,
                 const float* __restrict__ bias,
                 float* __restrict__ out)
{
    const int l = threadIdx.x & 63;
    const int q = l & 15;
    const int g = l >> 4;
    const int joff = (g == 1 || g == 2) ? 16 : 0;
    const int row  = (g & 1) ? 16 + q : q;
    const int h = blockIdx.x & (H_SZ - 1);
    const int b = blockIdx.x >> 6;
    const bool low32 = (l < 32);

    // ---- init-time convention probes (R8-proven) ----
    const int pr = __builtin_amdgcn_update_dpp(l, l, 0x121, 0xF, 0xF, false);
    const bool ror_minus = ((pr & 15) == ((q - 1) & 15));
    const v2u pp = __builtin_amdgcn_permlane16_swap((unsigned)l, (unsigned)l,
                                                    false, false);
    const bool sel_x = (pp.x == (unsigned)(l ^ 16));

    // ---- R row slice, pre-permuted for the probed rotation direction ----
    float rw[16];
    {
        const float* Rrow = R + (h * HD + row) * HD + joff;
        if (ror_minus) {
#pragma unroll
            for (int k = 0; k < 16; ++k) rw[k] = Rrow[(q - k) & 15];
        } else {
#pragma unroll
            for (int k = 0; k < 16; ++k) rw[k] = Rrow[(q + k) & 15];
        }
    }

    // ---- MFMA B fragments: B[k][n] = Wx[h][n][k] (f16), loaded once ----
    // lane: n = l&15 (tile0) / n+16 (tile1), k = (l>>4)*8 + [0..7]
    union AF { f16x8 v; f16x2 p[4]; };
    AF bf0, bf1;
    {
        const int n  = l & 15;
        const int k0 = (l >> 4) * 8;
        const float4* wp0 = (const float4*)(Wx + (h * HD + n) * HD + k0);
        const float4* wp1 = (const float4*)(Wx + (h * HD + n + 16) * HD + k0);
        float4 u = wp0[0], v = wp0[1];
        bf0.p[0] = __builtin_amdgcn_cvt_pkrtz(u.x, u.y);
        bf0.p[1] = __builtin_amdgcn_cvt_pkrtz(u.z, u.w);
        bf0.p[2] = __builtin_amdgcn_cvt_pkrtz(v.x, v.y);
        bf0.p[3] = __builtin_amdgcn_cvt_pkrtz(v.z, v.w);
        u = wp1[0]; v = wp1[1];
        bf1.p[0] = __builtin_amdgcn_cvt_pkrtz(u.x, u.y);
        bf1.p[1] = __builtin_amdgcn_cvt_pkrtz(u.z, u.w);
        bf1.p[2] = __builtin_amdgcn_cvt_pkrtz(v.x, v.y);
        bf1.p[3] = __builtin_amdgcn_cvt_pkrtz(v.z, v.w);
    }
    const float bn0 = bias[h * HD + (l & 15)];        // C-init carries bias
    const float bn1 = bias[h * HD + (l & 15) + 16];

    float hn = h0[(b * H_SZ + h) * HD + row];

    // ---- LDS: x tiles (gl_lds linear layout) + wx tiles (+1 row pad) ----
    __shared__ __align__(16) float xl[2][512];        // 2 x 2KB
    __shared__ float wxl[2][BLK + 1][32];             // pad row for prefetch

    // A-frag LDS word offsets: lane m = l&15, chunks J0=(l>>4)*2, J0+1
    const int m  = l & 15;
    const int J0 = (l >> 4) * 2, J1 = J0 + 1;
    const int aw0 = 64 * (J0 & 3) + 4 * m + 256 * (J0 >> 2);
    const int aw1 = 64 * (J1 & 3) + 4 * m + 256 * (J1 >> 2);

    // gl_lds source: call c stages (step = l&15, cols 4*(l>>4) + 16c .. +3)
    const float* gx0 = x + (long)(l & 15) * ST + (long)b * D_SZ + h * HD
                         + (l >> 4) * 4;
    const float* gx1 = gx0 + 16;

    float* op = out + (long)b * D_SZ + h * HD + row;

#define STAGE(nbuf, t0) do {                                                  \
        __builtin_amdgcn_global_load_lds((gas_t)(gx0 + (long)(t0) * ST),      \
                                         (las_t)&xl[nbuf][0],   16, 0, 0);    \
        __builtin_amdgcn_global_load_lds((gas_t)(gx1 + (long)(t0) * ST),      \
                                         (las_t)&xl[nbuf][256], 16, 0, 0);    \
    } while (0)

#define COMPUTE_WX(nbuf) do {                                                 \
        float4 xa = *(const float4*)&xl[nbuf][aw0];                           \
        float4 xc = *(const float4*)&xl[nbuf][aw1];                           \
        AF af;                                                                \
        af.p[0] = __builtin_amdgcn_cvt_pkrtz(xa.x, xa.y);                     \
        af.p[1] = __builtin_amdgcn_cvt_pkrtz(xa.z, xa.w);                     \
        af.p[2] = __builtin_amdgcn_cvt_pkrtz(xc.x, xc.y);                     \
        af.p[3] = __builtin_amdgcn_cvt_pkrtz(xc.z, xc.w);                     \
        f32x4 c0 = {bn0, bn0, bn0, bn0};                                      \
        f32x4 c1 = {bn1, bn1, bn1, bn1};                                      \
        c0 = __builtin_amdgcn_mfma_f32_16x16x32_f16(af.v, bf0.v, c0, 0, 0, 0);\
        c1 = __builtin_amdgcn_mfma_f32_16x16x32_f16(af.v, bf1.v, c1, 0, 0, 0);\
        const int mr = (l >> 4) * 4, nc = l & 15;                             \
        wxl[nbuf][mr + 0][nc] = c0[0]; wxl[nbuf][mr + 0][nc + 16] = c1[0];    \
        wxl[nbuf][mr + 1][nc] = c0[1]; wxl[nbuf][mr + 1][nc + 16] = c1[1];    \
        wxl[nbuf][mr + 2][nc] = c0[2]; wxl[nbuf][mr + 2][nc + 16] = c1[2];    \
        wxl[nbuf][mr + 3][nc] = c0[3]; wxl[nbuf][mr + 3][nc + 16] = c1[3];    \
    } while (0)

    // ---- prologue: block 0 ----
    STAGE(0, 0);
    asm volatile("s_waitcnt vmcnt(0)" ::: "memory");
    COMPUTE_WX(0);
    float wx_cur = wxl[0][0][row];

    for (int tb = 0; tb < T_STEPS; tb += BLK) {
        const int buf   = (tb >> 4) & 1;
        const bool more = (tb + BLK) < T_STEPS;
        if (more) STAGE(buf ^ 1, tb + BLK);   // side-effecting: cannot sink

        // ---- the scan: ROLLED on purpose ----
#pragma clang loop unroll(disable)
        for (int k = 0; k < BLK; ++k) {
            const float wxn = wxl[buf][k + 1][row];   // prefetch (pad at k=15)

            // dot-ready h (R8-proven probed select)
            const v2u hp = __builtin_amdgcn_permlane16_swap(
                __float_as_uint(hn), __float_as_uint(hn), false, false);
            const float from16 = __uint_as_float(sel_x ? hp.x : hp.y);
            const float hd = low32 ? hn : from16;

            // 16 R-FMAs, operands via DPP row_ror
            float r0 = rw[0] * hd;
            float r1 = rw[1] * ror16<1>(hd);
            float r2 = rw[2] * ror16<2>(hd);
            float r3 = rw[3] * ror16<3>(hd);
#define ACC4(B) \
            r0 = fmaf(rw[(B)+0], ror16<(B)+0>(hd), r0); \
            r1 = fmaf(rw[(B)+1], ror16<(B)+1>(hd), r1); \
            r2 = fmaf(rw[(B)+2], ror16<(B)+2>(hd), r2); \
            r3 = fmaf(rw[(B)+3], ror16<(B)+3>(hd), r3);
            ACC4(4)
            ACC4(8)
            ACC4(12)
#undef ACC4
            const float s = (r0 + r1) + (r2 + r3);

            // half-combine (convention-invariant: own + partner)
            const v2u sp = __builtin_amdgcn_permlane32_swap(
                __float_as_uint(s), __float_as_uint(s), false, false);
            const float pre = (__uint_as_float(sp.x) + __uint_as_float(sp.y))
                            + wx_cur;

            hn = pre * __builtin_amdgcn_rcpf(1.0f + fabsf(pre));

            op[0] = hn;            // duplicate lanes write identical values
            op += ST;
            wx_cur = wxn;
        }

        if (more) {
            // in-order vmcnt: 16 younger ys-stores outstanding, the 2 gl_lds
            // are the oldest -> vmcnt(16) guarantees x[n+1] is LDS-resident.
            asm volatile("s_waitcnt vmcnt(16)" ::: "memory");
            COMPUTE_WX(buf ^ 1);
            wx_cur = wxl[buf ^ 1][0][row];
        }
    }

    out[(long)T_STEPS * ST + (b * H_SZ + h) * HD + row] = hn;
#undef STAGE
#undef COMPUTE_WX
}

extern "C" void kernel_launch(void* const* d_in, const int* in_sizes, int n_in,
                              void* d_out, int out_size, void* d_ws, size_t ws_size,
                              hipStream_t stream) {
    const float* x    = (const float*)d_in[0];
    const float* h0   = (const float*)d_in[1];
    const float* R    = (const float*)d_in[2];
    const float* Wx   = (const float*)d_in[3];
    const float* bias = (const float*)d_in[4];
    float* out = (float*)d_out;

    elman_fused<<<dim3(B_SZ * H_SZ), dim3(64), 0, stream>>>(x, h0, R, Wx, bias, out);
}